// Round 1
// baseline (425.643 us; speedup 1.0000x reference)
//
#include <hip/hip_runtime.h>

// 3D Haar DWT, x:(2,32,64,128,128) fp32 -> low:(2,32,32,64,64) ++ highs:(2,32,7,32,64,64)
// Memory-bound: 256 MiB in + 256 MiB out. Butterfly formulation, one scale mul.
//
// Thread mapping: tid bits = w2[0:5) | h[5:11) | d[11:16) | bc[16:22)
//   each thread: 4x float4 loads (input rows (2d,2h),(2d,2h+1),(2d+1,2h),(2d+1,2h+1),
//   w-range [4*w2,4*w2+4)), 8x float2 stores (one per sub-band).

__device__ __forceinline__ float2 f2add(float2 a, float2 b) { return make_float2(a.x + b.x, a.y + b.y); }
__device__ __forceinline__ float2 f2sub(float2 a, float2 b) { return make_float2(a.x - b.x, a.y - b.y); }
__device__ __forceinline__ float2 f2scale(float2 a, float s) { return make_float2(a.x * s, a.y * s); }

__global__ __launch_bounds__(256) void dwt3d_haar_kernel(
    const float4* __restrict__ x,   // input as float4 (W=128 floats = 32 float4 per row)
    const float* __restrict__ kern, // 8x2x2x2 taps; |tap| uniform = kern[0]
    float2* __restrict__ out)       // output as float2 (Wh=64 floats = 32 float2 per row)
{
    const float scale = kern[0];  // fl(fl((1/sqrt2)^2)*(1/sqrt2)) — bit-matches reference magnitude

    const unsigned tid = blockIdx.x * 256u + threadIdx.x;
    const unsigned w2 = tid & 31u;          // output float2 column, 0..31
    const unsigned h  = (tid >> 5) & 63u;   // output row, 0..63
    const unsigned d  = (tid >> 11) & 31u;  // output depth, 0..31
    const unsigned bc = tid >> 16;          // fused batch*channel, 0..63

    // ---- input loads (float4 units: row=32, plane=128*32, vol=64*128*32) ----
    const size_t base = (((size_t)bc * 64u + 2u * d) * 128u + 2u * h) * 32u + w2;
    const float4 v00 = x[base];               // z=2d,   y=2h
    const float4 v01 = x[base + 32u];         // z=2d,   y=2h+1
    const float4 v10 = x[base + 4096u];       // z=2d+1, y=2h   (128*32)
    const float4 v11 = x[base + 4096u + 32u]; // z=2d+1, y=2h+1

    // ---- W butterfly (within each float4: pairs (x,y) and (z,w)) ----
    const float2 s00 = make_float2(v00.x + v00.y, v00.z + v00.w);
    const float2 d00 = make_float2(v00.x - v00.y, v00.z - v00.w);
    const float2 s01 = make_float2(v01.x + v01.y, v01.z + v01.w);
    const float2 d01 = make_float2(v01.x - v01.y, v01.z - v01.w);
    const float2 s10 = make_float2(v10.x + v10.y, v10.z + v10.w);
    const float2 d10 = make_float2(v10.x - v10.y, v10.z - v10.w);
    const float2 s11 = make_float2(v11.x + v11.y, v11.z + v11.w);
    const float2 d11 = make_float2(v11.x - v11.y, v11.z - v11.w);

    // ---- H butterfly ----
    const float2 hs_s0 = f2add(s00, s01), hd_s0 = f2sub(s00, s01); // z=0: y-sum/diff of w-sums
    const float2 hs_d0 = f2add(d00, d01), hd_d0 = f2sub(d00, d01); // z=0: of w-diffs
    const float2 hs_s1 = f2add(s10, s11), hd_s1 = f2sub(s10, s11); // z=1
    const float2 hs_d1 = f2add(d10, d11), hd_d1 = f2sub(d10, d11);

    // ---- D butterfly + scale; s = zbit*4 + ybit*2 + xbit ----
    const float2 o0 = f2scale(f2add(hs_s0, hs_s1), scale); // LLL
    const float2 o1 = f2scale(f2add(hs_d0, hs_d1), scale); // LLH
    const float2 o2 = f2scale(f2add(hd_s0, hd_s1), scale); // LHL
    const float2 o3 = f2scale(f2add(hd_d0, hd_d1), scale); // LHH
    const float2 o4 = f2scale(f2sub(hs_s0, hs_s1), scale); // HLL
    const float2 o5 = f2scale(f2sub(hs_d0, hs_d1), scale); // HLH
    const float2 o6 = f2scale(f2sub(hd_s0, hd_s1), scale); // HHL
    const float2 o7 = f2scale(f2sub(hd_d0, hd_d1), scale); // HHH

    // ---- stores (float2 units; per-(bc,subband) plane = 32*64*32 = 65536) ----
    const size_t spatial = (size_t)d * 2048u + (size_t)h * 32u + w2; // d*(64*32)+h*32+w2
    const size_t lowTotal = 64u * 65536u;                            // 4,194,304 float2

    out[(size_t)bc * 65536u + spatial] = o0; // low

    const size_t hiBase = lowTotal + (size_t)bc * (7u * 65536u) + spatial;
    out[hiBase + 0u * 65536u] = o1;
    out[hiBase + 1u * 65536u] = o2;
    out[hiBase + 2u * 65536u] = o3;
    out[hiBase + 3u * 65536u] = o4;
    out[hiBase + 4u * 65536u] = o5;
    out[hiBase + 5u * 65536u] = o6;
    out[hiBase + 6u * 65536u] = o7;
}

extern "C" void kernel_launch(void* const* d_in, const int* in_sizes, int n_in,
                              void* d_out, int out_size, void* d_ws, size_t ws_size,
                              hipStream_t stream) {
    const float4* x = (const float4*)d_in[0];
    const float* kern = (const float*)d_in[1];
    float2* out = (float2*)d_out;

    // 2*32*32*64*32 = 4,194,304 threads
    const unsigned nThreads = 4194304u;
    dwt3d_haar_kernel<<<nThreads / 256u, 256u, 0, stream>>>(x, kern, out);
}

// Round 2
// 416.818 us; speedup vs baseline: 1.0212x; 1.0212x over previous
//
#include <hip/hip_runtime.h>

// 3D Haar DWT, x:(2,32,64,128,128) fp32 -> low:(2,32,32,64,64) ++ highs:(2,32,7,32,64,64)
// Memory-bound: 256 MiB in + 256 MiB out, every byte touched exactly once.
// R2: nontemporal loads/stores (streaming, bypass L2 allocate) on the R1 butterfly mapping.
//
// Thread mapping: tid bits = w2[0:5) | h[5:11) | d[11:16) | bc[16:22)
//   each thread: 4x 16B loads (rows (2d,2h),(2d,2h+1),(2d+1,2h),(2d+1,2h+1)),
//   8x 8B stores (one per sub-band). All wave accesses 512B-contiguous.

typedef float f32x2 __attribute__((ext_vector_type(2)));
typedef float f32x4 __attribute__((ext_vector_type(4)));

__global__ __launch_bounds__(256) void dwt3d_haar_kernel(
    const f32x4* __restrict__ x,   // input as float4 (W=128 floats = 32 float4 per row)
    const float* __restrict__ kern, // 8x2x2x2 taps; |tap| uniform = kern[0]
    f32x2* __restrict__ out)       // output as float2 (Wh=64 floats = 32 float2 per row)
{
    const float scale = kern[0];  // bit-matches reference tap magnitude

    const unsigned tid = blockIdx.x * 256u + threadIdx.x;
    const unsigned w2 = tid & 31u;          // output float2 column, 0..31
    const unsigned h  = (tid >> 5) & 63u;   // output row, 0..63
    const unsigned d  = (tid >> 11) & 31u;  // output depth, 0..31
    const unsigned bc = tid >> 16;          // fused batch*channel, 0..63

    // ---- input loads (float4 units: row=32, plane=128*32=4096, vol=64*4096) ----
    const size_t base = (((size_t)bc * 64u + 2u * d) * 128u + 2u * h) * 32u + w2;
    const f32x4 v00 = __builtin_nontemporal_load(&x[base]);               // z=2d,   y=2h
    const f32x4 v01 = __builtin_nontemporal_load(&x[base + 32u]);         // z=2d,   y=2h+1
    const f32x4 v10 = __builtin_nontemporal_load(&x[base + 4096u]);       // z=2d+1, y=2h
    const f32x4 v11 = __builtin_nontemporal_load(&x[base + 4096u + 32u]); // z=2d+1, y=2h+1

    // ---- W butterfly: even={x,z}, odd={y,w} -> {x±y, z±w} ----
    const f32x2 s00 = v00.even + v00.odd, d00 = v00.even - v00.odd;
    const f32x2 s01 = v01.even + v01.odd, d01 = v01.even - v01.odd;
    const f32x2 s10 = v10.even + v10.odd, d10 = v10.even - v10.odd;
    const f32x2 s11 = v11.even + v11.odd, d11 = v11.even - v11.odd;

    // ---- H butterfly ----
    const f32x2 hs_s0 = s00 + s01, hd_s0 = s00 - s01;
    const f32x2 hs_d0 = d00 + d01, hd_d0 = d00 - d01;
    const f32x2 hs_s1 = s10 + s11, hd_s1 = s10 - s11;
    const f32x2 hs_d1 = d10 + d11, hd_d1 = d10 - d11;

    // ---- D butterfly + scale; s = zbit*4 + ybit*2 + xbit ----
    const f32x2 o0 = (hs_s0 + hs_s1) * scale; // LLL
    const f32x2 o1 = (hs_d0 + hs_d1) * scale; // LLH
    const f32x2 o2 = (hd_s0 + hd_s1) * scale; // LHL
    const f32x2 o3 = (hd_d0 + hd_d1) * scale; // LHH
    const f32x2 o4 = (hs_s0 - hs_s1) * scale; // HLL
    const f32x2 o5 = (hs_d0 - hs_d1) * scale; // HLH
    const f32x2 o6 = (hd_s0 - hd_s1) * scale; // HHL
    const f32x2 o7 = (hd_d0 - hd_d1) * scale; // HHH

    // ---- stores (float2 units; per-(bc,subband) plane = 32*64*32 = 65536) ----
    const size_t spatial = (size_t)d * 2048u + (size_t)h * 32u + w2;
    const size_t lowTotal = 64u * 65536u; // 4,194,304 float2

    __builtin_nontemporal_store(o0, &out[(size_t)bc * 65536u + spatial]); // low

    f32x2* hi = out + lowTotal + (size_t)bc * (7u * 65536u) + spatial;
    __builtin_nontemporal_store(o1, hi + 0u * 65536u);
    __builtin_nontemporal_store(o2, hi + 1u * 65536u);
    __builtin_nontemporal_store(o3, hi + 2u * 65536u);
    __builtin_nontemporal_store(o4, hi + 3u * 65536u);
    __builtin_nontemporal_store(o5, hi + 4u * 65536u);
    __builtin_nontemporal_store(o6, hi + 5u * 65536u);
    __builtin_nontemporal_store(o7, hi + 6u * 65536u);
}

extern "C" void kernel_launch(void* const* d_in, const int* in_sizes, int n_in,
                              void* d_out, int out_size, void* d_ws, size_t ws_size,
                              hipStream_t stream) {
    const f32x4* x = (const f32x4*)d_in[0];
    const float* kern = (const float*)d_in[1];
    f32x2* out = (f32x2*)d_out;

    // 2*32*32*64*32 = 4,194,304 threads
    dwt3d_haar_kernel<<<4194304u / 256u, 256u, 0, stream>>>(x, kern, out);
}